// Round 10
// baseline (392.148 us; speedup 1.0000x reference)
//
#include <hip/hip_runtime.h>
#include <hip/hip_bf16.h>
#include <math.h>

#define B_ 8
#define N_ 1024
#define H_ 14
#define DH_ 64
#define D_ 896
#define M_ (B_*N_)        // 8192 rows
#define DQKV_ 2688        // 3*D_

// exp2-domain constants: 2*log2(e), log2(e)*(1 - M0) with M0 = 12
#define TWO_LOG2E_ 2.8853900817779268f
#define BIAS_C_   (-15.869645449778597f)
#define QSCALE_     0.18033688011112043f   // 0.125 * log2(e), folded into Q at GEMM epilogue
#define RAD_        0.017453292519943295f

typedef __attribute__((ext_vector_type(8))) short bf16x8;
typedef __attribute__((ext_vector_type(4))) short bf16x4;
typedef __attribute__((ext_vector_type(4))) float f32x4;

__device__ __forceinline__ float bf2f(short s){
  unsigned u = ((unsigned)(unsigned short)s) << 16;
  union { unsigned u; float f; } c; c.u = u; return c.f;
}
__device__ __forceinline__ short f2bf(float f){
  union { float f; unsigned u; } c; c.f = f;
  unsigned u = c.u;
  unsigned r = (u + 0x7FFFu + ((u >> 16) & 1u)) >> 16;
  return (short)(unsigned short)r;
}
__device__ __forceinline__ float asf(unsigned u){
  union { unsigned u; float f; } c; c.u = u; return c.f;
}
// pack 2 f32 -> 2 bf16 in one VALU op (RNE -- bit-identical to f2bf above)
__device__ __forceinline__ unsigned cvt_pk_bf16(float lo, float hi){
  unsigned r;
  asm("v_cvt_pk_bf16_f32 %0, %1, %2" : "=v"(r) : "v"(lo), "v"(hi));
  return r;
}

// 16x16x16 bf16 MFMA: builtin when available, else ISA-verified inline asm.
#if __has_builtin(__builtin_amdgcn_mfma_f32_16x16x16bf16_1k)
#define MFMA16(D, A, B) (D) = __builtin_amdgcn_mfma_f32_16x16x16bf16_1k((A), (B), (D), 0, 0, 0)
#else
#define MFMA16(D, A, B) asm("v_mfma_f32_16x16x16_bf16 %0, %1, %2, %0" : "+v"(D) : "v"(A), "v"(B))
#endif

// raw workgroup barrier: LDS visibility only (lgkm), does NOT drain vmcnt ->
// global register-prefetches stay in flight across it.
#define BAR_LDS() do { asm volatile("s_waitcnt lgkmcnt(0)" ::: "memory"); \
                       __builtin_amdgcn_s_barrier(); } while (0)

// ---------------- LayerNorm: one block per row, f32 in -> bf16 out ----------------
__global__ __launch_bounds__(256) void ln_kernel(const float* __restrict__ x,
                                                 const float* __restrict__ g,
                                                 const float* __restrict__ bb,
                                                 short* __restrict__ y)
{
  int row = blockIdx.x;
  const float* xr = x + (size_t)row * D_;
  float s = 0.f, s2 = 0.f;
  for (int i = threadIdx.x; i < D_; i += 256){
    float v = xr[i]; s += v; s2 = fmaf(v, v, s2);
  }
  #pragma unroll
  for (int off = 32; off > 0; off >>= 1){
    s  += __shfl_down(s,  off, 64);
    s2 += __shfl_down(s2, off, 64);
  }
  __shared__ float rs_[4], rs2_[4];
  int wv = threadIdx.x >> 6;
  if ((threadIdx.x & 63) == 0){ rs_[wv] = s; rs2_[wv] = s2; }
  __syncthreads();
  float ts  = rs_[0] + rs_[1] + rs_[2] + rs_[3];
  float ts2 = rs2_[0] + rs2_[1] + rs2_[2] + rs2_[3];
  float mu  = ts * (1.f / D_);
  float var = ts2 * (1.f / D_) - mu * mu;
  float rstd = rsqrtf(var + 1e-5f);
  short* yr = y + (size_t)row * D_;
  for (int i = threadIdx.x; i < D_; i += 256){
    yr[i] = f2bf((xr[i] - mu) * rstd * g[i] + bb[i]);
  }
}

// ---------------- Transpose weights: f32 W[k][n] -> bf16 Wt[n][k] ----------------
__global__ __launch_bounds__(256) void transpose_kernel(
    const float* __restrict__ Wq, const float* __restrict__ Wk,
    const float* __restrict__ Wv, const float* __restrict__ Wo,
    short* __restrict__ WqkvT, short* __restrict__ WoT)
{
  __shared__ short t[64][72];
  int z = blockIdx.z;
  const float* W = (z == 0) ? Wq : (z == 1) ? Wk : (z == 2) ? Wv : Wo;
  int kb = blockIdx.x * 64, nb = blockIdx.y * 64;
  int c0 = (threadIdx.x & 7) * 8;
  int r0 = threadIdx.x >> 3;            // 0..31
  #pragma unroll
  for (int rr = 0; rr < 64; rr += 32){
    const float* src = &W[(size_t)(kb + r0 + rr) * D_ + nb + c0];
    float4 a = *(const float4*)src;
    float4 b = *(const float4*)(src + 4);
    short* dstl = &t[r0 + rr][c0];
    dstl[0] = f2bf(a.x); dstl[1] = f2bf(a.y); dstl[2] = f2bf(a.z); dstl[3] = f2bf(a.w);
    dstl[4] = f2bf(b.x); dstl[5] = f2bf(b.y); dstl[6] = f2bf(b.z); dstl[7] = f2bf(b.w);
  }
  __syncthreads();
  short* dst = (z < 3) ? (WqkvT + (size_t)(z * D_) * D_) : WoT;
  #pragma unroll
  for (int rr = 0; rr < 64; rr += 32){
    int n = nb + r0 + rr;
    bf16x8 v;
    #pragma unroll
    for (int j = 0; j < 8; j++) v[j] = t[c0 + j][r0 + rr];
    *(bf16x8*)&dst[(size_t)n * D_ + kb + c0] = v;
  }
}

// ---------------- V transpose: QKV V-part [tok][d] -> VT[(b,h,d)][tok] bf16 ----------
__global__ __launch_bounds__(256) void vt_kernel(const short* __restrict__ QKV,
                                                 short* __restrict__ VT)
{
  __shared__ short tt[64][72];
  int kt = blockIdx.x;                 // token tile 0..15
  int bh = blockIdx.y;                 // 0..111
  int b  = bh / H_, hh = bh - b * H_;
  int r  = threadIdx.x >> 2;           // 0..63
  int c0 = (threadIdx.x & 3) * 16;     // 0,16,32,48
  const short* src = QKV + ((size_t)(b * N_) + kt * 64 + r) * DQKV_ + 2 * D_ + hh * DH_ + c0;
  *(bf16x8*)&tt[r][c0]     = *(const bf16x8*)src;
  *(bf16x8*)&tt[r][c0 + 8] = *(const bf16x8*)(src + 8);
  __syncthreads();
  short* dst = VT + ((size_t)bh * DH_ + r) * N_ + kt * 64 + c0;
  bf16x8 v0, v1;
  #pragma unroll
  for (int j = 0; j < 8; j++){ v0[j] = tt[c0 + j][r]; v1[j] = tt[c0 + 8 + j][r]; }
  *(bf16x8*)dst       = v0;
  *(bf16x8*)(dst + 8) = v1;
}

// ---------------- Prep: csb[k][q] (PRE=0) OR alignQ[b][q][k] + adjQ[q][k] (PRE=1) ----
// adjQ bf16 replicates r1-r4's bf16 adjT numerics (mask sign preserved by RNE).
__global__ __launch_bounds__(256) void prep_kernel(
    const float* __restrict__ adj, const float* __restrict__ brg,
    const float* __restrict__ wdir,
    unsigned* __restrict__ csb, short* __restrict__ alignQ,
    short* __restrict__ adjQ, int do_align)
{
  int kt = blockIdx.x, qt = blockIdx.y;
  __shared__ float brgS[64][65];
  __shared__ float cA_[8][64], sA_[8][64];
  int r  = threadIdx.x >> 2;          // 0..63
  int c0 = (threadIdx.x & 3) * 16;    // 0,16,32,48

  float bb[16];
  {
    const float* bp = brg + (size_t)(kt * 64 + r) * N_ + qt * 64 + c0;
    #pragma unroll
    for (int i = 0; i < 16; i += 4){
      float4 bv = *(const float4*)(bp + i);
      bb[i] = bv.x; bb[i+1] = bv.y; bb[i+2] = bv.z; bb[i+3] = bv.w;
    }
  }

  if (do_align){
    #pragma unroll
    for (int i = 0; i < 16; i++) brgS[r][c0 + i] = bb[i];
    for (int idx = threadIdx.x; idx < 512; idx += 256){
      int b = idx >> 6, qq = idx & 63;
      float A = wdir[(size_t)b * N_ + qt * 64 + qq] * RAD_;
      float s, c; __sincosf(A, &s, &c);
      sA_[b][qq] = s; cA_[b][qq] = c;
    }
    // adjQ[q][k] bf16 (coalesced read + write, no transpose)
    {
      const float* ap = adj + (size_t)(qt * 64 + r) * N_ + kt * 64 + c0;
      unsigned w8[8];
      #pragma unroll
      for (int i = 0; i < 16; i += 4){
        float4 av = *(const float4*)(ap + i);
        w8[i/2]     = cvt_pk_bf16(av.x, av.y);
        w8[i/2 + 1] = cvt_pk_bf16(av.z, av.w);
      }
      short* dst = adjQ + (size_t)(qt * 64 + r) * N_ + kt * 64 + c0;
      *(uint4*)dst       = make_uint4(w8[0], w8[1], w8[2], w8[3]);
      *(uint4*)(dst + 8) = make_uint4(w8[4], w8[5], w8[6], w8[7]);
    }
    __syncthreads();
    // roles swap: r = q-local, c0 = k-local base
    float cB[16], sB[16];
    #pragma unroll
    for (int i = 0; i < 16; i++){
      float Br = (brgS[c0 + i][r] + 180.f) * RAD_;
      __sincosf(Br, &sB[i], &cB[i]);
    }
    #pragma unroll
    for (int b = 0; b < 8; b++){
      float ca = cA_[b][r], sa = sA_[b][r];
      unsigned w8[8];
      #pragma unroll
      for (int p = 0; p < 8; p++){
        float a0 = fmaf(ca, cB[2*p],     sa * sB[2*p]);
        float a1 = fmaf(ca, cB[2*p + 1], sa * sB[2*p + 1]);
        w8[p] = cvt_pk_bf16(a0, a1);
      }
      short* dst = alignQ + ((size_t)b * N_ + qt * 64 + r) * N_ + kt * 64 + c0;
      *(uint4*)dst       = make_uint4(w8[0], w8[1], w8[2], w8[3]);
      *(uint4*)(dst + 8) = make_uint4(w8[4], w8[5], w8[6], w8[7]);
    }
  } else {
    unsigned* cp = csb + (size_t)(kt * 64 + r) * N_ + qt * 64 + c0;
    #pragma unroll
    for (int i = 0; i < 16; i += 4){
      unsigned o[4];
      #pragma unroll
      for (int j = 0; j < 4; j++){
        float Br = (bb[i + j] + 180.f) * RAD_;
        float sBv, cBv; __sincosf(Br, &sBv, &cBv);
        o[j] = ((unsigned)(unsigned short)f2bf(cBv)) |
               (((unsigned)(unsigned short)f2bf(sBv)) << 16);
      }
      *(uint4*)(cp + i) = make_uint4(o[0], o[1], o[2], o[3]);
    }
  }
}

// ---------------- MFMA GEMM: C[M x N] = A[M x K] * Bt[N x K]^T ----------------
__global__ __launch_bounds__(256) void gemm_bt(const short* __restrict__ A,
                                               const short* __restrict__ Bt,
                                               short* __restrict__ C,
                                               float* __restrict__ Cf,
                                               const float* __restrict__ residf,
                                               int N, int rope)
{
  const int K = D_;
  __shared__ short As[128 * 32];
  __shared__ short Bs[128 * 32];
  int tid  = threadIdx.x;
  int wave = tid >> 6;
  int lane = tid & 63;
  int quad = lane >> 4;
  int l16  = lane & 15;
  int wr = wave >> 1, wc = wave & 1;
  int m0 = blockIdx.x * 128;
  int n0 = blockIdx.y * 128;

  f32x4 acc[4][4];
  #pragma unroll
  for (int i = 0; i < 4; i++)
    #pragma unroll
    for (int j = 0; j < 4; j++)
      acc[i][j] = (f32x4){0.f, 0.f, 0.f, 0.f};

  for (int k0 = 0; k0 < K; k0 += 32){
    __syncthreads();
    #pragma unroll
    for (int it = 0; it < 2; ++it){
      int c   = tid + it * 256;
      int row = c >> 2;
      int cc  = c & 3;
      const short* ga = A  + (size_t)(m0 + row) * K + k0 + cc * 8;
      const short* gb = Bt + (size_t)(n0 + row) * K + k0 + cc * 8;
      short* la = As + (size_t)(wave * 64 + it * 256) * 8;
      short* lb = Bs + (size_t)(wave * 64 + it * 256) * 8;
      __builtin_amdgcn_global_load_lds((const __attribute__((address_space(1))) void*)ga,
                                       (__attribute__((address_space(3))) void*)la, 16, 0, 0);
      __builtin_amdgcn_global_load_lds((const __attribute__((address_space(1))) void*)gb,
                                       (__attribute__((address_space(3))) void*)lb, 16, 0, 0);
    }
    __syncthreads();

    bf16x8 af[4], bfr[4];
    #pragma unroll
    for (int i = 0; i < 4; i++)
      af[i] = *(const bf16x8*)(As + (size_t)(wr * 64 + i * 16 + l16) * 32 + quad * 8);
    #pragma unroll
    for (int j = 0; j < 4; j++)
      bfr[j] = *(const bf16x8*)(Bs + (size_t)(wc * 64 + j * 16 + l16) * 32 + quad * 8);
    #pragma unroll
    for (int i = 0; i < 4; i++)
      #pragma unroll
      for (int j = 0; j < 4; j++)
        acc[i][j] = __builtin_amdgcn_mfma_f32_16x16x32_bf16(af[i], bfr[j], acc[i][j], 0, 0, 0);
  }

  if (rope){
    int cb  = n0 + wc * 64;            // head base col (64-aligned)
    int mat = cb / D_;                 // 0=Q, 1=K, 2=V
    if (mat < 2){
      float scale = (mat == 0) ? QSCALE_ : 1.0f;
      float invf0 = exp2f(-0.4152410118609203f * (float)l16);  // 10000^(-l16/32)
      float invf1 = invf0 * 0.01f;                             // 10000^(-(16+l16)/32)
      #pragma unroll
      for (int i = 0; i < 4; i++){
        #pragma unroll
        for (int rr = 0; rr < 4; rr++){
          int r = m0 + wr * 64 + i * 16 + quad * 4 + rr;
          float nseq = (float)(r & (N_ - 1));
          float s0, c0v, s1, c1v;
          __sincosf(nseq * invf0, &s0, &c0v);
          __sincosf(nseq * invf1, &s1, &c1v);
          float x1 = acc[i][0][rr], x2 = acc[i][2][rr];
          acc[i][0][rr] = (x1 * c0v - x2 * s0) * scale;
          acc[i][2][rr] = (x2 * c0v + x1 * s0) * scale;
          x1 = acc[i][1][rr]; x2 = acc[i][3][rr];
          acc[i][1][rr] = (x1 * c1v - x2 * s1) * scale;
          acc[i][3][rr] = (x2 * c1v + x1 * s1) * scale;
        }
      }
    }
  }

  #pragma unroll
  for (int i = 0; i < 4; i++){
    #pragma unroll
    for (int rr = 0; rr < 4; rr++){
      int r = m0 + wr * 64 + i * 16 + quad * 4 + rr;
      size_t rowoff = (size_t)r * N;
      #pragma unroll
      for (int j = 0; j < 4; j++){
        int cidx = n0 + wc * 64 + j * 16 + l16;
        float v = acc[i][j][rr];
        if (Cf){
          Cf[rowoff + cidx] = v + residf[rowoff + cidx];
        } else {
          C[rowoff + cidx] = f2bf(v);
        }
      }
    }
  }
}

// ---------------- Swapped-operand flash attention, 2 q-groups per wave --------------
// r9 info: halving barriers was NEUTRAL -> sync isn't the cost; the wall (345k cyc)
// vs VALU issue (135k cyc/SIMD) gap is UNCOVERED DEP LATENCY (1 serial chain/wave,
// ~3 waves/SIMD). Fix: each wave owns TWO independent 16-row q-groups sharing the
// block's K/V tiles -> 2 interleavable QK->SM->PV chains per wave (g1's MFMA hides
// g0's softmax VALU and vice versa). Block = 128 q-rows; grid 896. Bias inputs all
// bf16 (alignQ + adjQ) loaded per-group at QK start (transient regs, VGPR <= ~126).
// Single-buffer LDS 18.9KB, r7's 2-barrier protocol (verbatim), register-P kept.
template<int PRE>
__global__ __launch_bounds__(256, 2) void attn_kernel(
    const short* __restrict__ QKV,
    const short* __restrict__ VT,       // [(b*H+h)*64 + d][tok] bf16
    const unsigned* __restrict__ csb,   // [k][q] packed (cosB, sinB)   (PRE=0)
    const float* __restrict__ adjF,     // [q][k] f32 (raw input)       (PRE=0)
    const short* __restrict__ alignQ,   // [b][q][k] bf16               (PRE=1)
    const short* __restrict__ adjQ,     // [q][k] bf16                  (PRE=1)
    const float* __restrict__ wind_dirs,
    const float* __restrict__ wind_w,
    const float* __restrict__ wind_b,
    short* __restrict__ outb)
{
  __shared__ short K_s[64 * 72];       // K[k][d]
  __shared__ short V_t[64 * 76];       // V^T[d][k]

  int bid = blockIdx.x;
  // bid = qt*112 + hh*8 + b  (112%8==0 -> XCD = bid%8 = b); qt in 0..7
  int qt  = bid / 112;
  int rem = bid - qt * 112;
  int hh  = rem >> 3;
  int b   = rem & 7;
  int q0  = qt * 128;
  int kt0 = (qt * 2) & 15;             // staggered start tile (order-invariant)

  int t    = threadIdx.x;
  int w    = t >> 6;          // 0..3
  int lane = t & 63;
  int quad = lane >> 4;
  int l16  = lane & 15;
  // two q rows per lane: g=0 -> q0 + w*16 + l16 ; g=1 -> +64
  int qA = q0 + w * 16 + l16;
  int qB = qA + 64;

  // Q B-frags per group (x32 QK: B[n=q][d=quad*8+j], halves d<32 / d>=32)
  bf16x8 qb[2][2];
  {
    const short* qpA = QKV + ((size_t)(b * N_) + qA) * DQKV_ + hh * DH_ + quad * 8;
    const short* qpB = QKV + ((size_t)(b * N_) + qB) * DQKV_ + hh * DH_ + quad * 8;
    qb[0][0] = *(const bf16x8*)qpA;  qb[0][1] = *(const bf16x8*)(qpA + 32);
    qb[1][0] = *(const bf16x8*)qpB;  qb[1][1] = *(const bf16x8*)(qpB + 32);
  }

  float cAq[2], sAq[2];
  if (!PRE){
    #pragma unroll
    for (int g = 0; g < 2; g++){
      float A = wind_dirs[(size_t)b * N_ + qA + g * 64] * RAD_;
      sAq[g] = __sinf(A); cAq[g] = __cosf(A);
    }
  }
  float w0m = wind_w[hh]      * TWO_LOG2E_;
  float w1m = wind_w[H_ + hh] * TWO_LOG2E_;
  float wbm = wind_b[hh]      * TWO_LOG2E_;

  float lsum[2] = {0.f, 0.f};
  f32x4 OT[2][4];                      // OT[g][db]: O[d=db*16+quad*4+rr][q_g]
  #pragma unroll
  for (int g = 0; g < 2; g++)
    #pragma unroll
    for (int db = 0; db < 4; db++) OT[g][db] = (f32x4){0.f, 0.f, 0.f, 0.f};

  // staging: 4 threads/row, 2x16B each (r7 addressing, verbatim)
  int sr = t >> 2, sc = (t & 3) * 16;
  const short* kg0 = QKV + ((size_t)(b * N_) + sr) * DQKV_ + D_ + hh * DH_ + sc;
  const short* vg0 = VT + ((size_t)(b * H_ + hh) * DH_ + sr) * N_ + sc;

  // per-lane bias row bases (k-contiguous)
  const short* alA = alignQ + ((size_t)b * N_ + qA) * N_ + quad * 4;
  const short* ajA = adjQ + (size_t)qA * N_ + quad * 4;
  const float* adA = adjF + (size_t)qA * N_ + quad * 4;

  int k0f = kt0 * 64;
  // prologue prefetch (tile kt0): K/V staging registers
  bf16x8 pkA = *(const bf16x8*)(kg0 + (size_t)k0f * DQKV_);
  bf16x8 pkB = *(const bf16x8*)(kg0 + (size_t)k0f * DQKV_ + 8);
  bf16x8 pvA = *(const bf16x8*)(vg0 + k0f);
  bf16x8 pvB = *(const bf16x8*)(vg0 + k0f + 8);

  for (int it = 0; it < 16; ++it){
    int k0 = ((it + kt0) & 15) * 64;
    int kn = ((it + 1 + kt0) & 15) * 64;

    BAR_LDS();                         // WAR: prev tile's LDS reads all consumed
    *(bf16x8*)(K_s + sr * 72 + sc)     = pkA;
    *(bf16x8*)(K_s + sr * 72 + sc + 8) = pkB;
    *(bf16x8*)(V_t + sr * 76 + sc)     = pvA;
    *(bf16x8*)(V_t + sr * 76 + sc + 8) = pvB;
    BAR_LDS();                         // RAW: staging visible; vmcnt NOT drained

    // issue next tile's K/V prefetch -- in flight under the whole compute phase
    pkA = *(const bf16x8*)(kg0 + (size_t)kn * DQKV_);
    pkB = *(const bf16x8*)(kg0 + (size_t)kn * DQKV_ + 8);
    pvA = *(const bf16x8*)(vg0 + kn);
    pvB = *(const bf16x8*)(vg0 + kn + 8);

    #pragma unroll
    for (int g = 0; g < 2; g++){
      size_t grow = (size_t)g * 64 * N_;   // q_g row offset in [q][k] tables

      // issue this group's bias loads first (consumed after QK, ~8 MFMAs later)
      bf16x4 al4[4], aj4[4]; float4 ad4[4]; unsigned cs4[4][4];
      #pragma unroll
      for (int jc = 0; jc < 4; jc++){
        if (PRE){
          al4[jc] = *(const bf16x4*)(alA + grow + k0 + jc * 16);
          aj4[jc] = *(const bf16x4*)(ajA + grow + k0 + jc * 16);
        } else {
          ad4[jc] = *(const float4*)(adA + grow + k0 + jc * 16);
          #pragma unroll
          for (int rr = 0; rr < 4; rr++)
            cs4[jc][rr] = csb[(size_t)(k0 + jc * 16 + quad * 4 + rr) * N_ + qA + g * 64];
        }
      }

      // S^T = K . Q_g^T  (lane: k = jc*16 + quad*4 + rr, q = q_g)
      f32x4 S[4];
      __builtin_amdgcn_s_setprio(1);
      #pragma unroll
      for (int jc = 0; jc < 4; jc++){
        bf16x8 ka0 = *(const bf16x8*)(K_s + (jc * 16 + l16) * 72 + quad * 8);
        bf16x8 ka1 = *(const bf16x8*)(K_s + (jc * 16 + l16) * 72 + 32 + quad * 8);
        f32x4 s = (f32x4){0.f, 0.f, 0.f, 0.f};
        s = __builtin_amdgcn_mfma_f32_16x16x32_bf16(ka0, qb[g][0], s, 0, 0, 0);
        s = __builtin_amdgcn_mfma_f32_16x16x32_bf16(ka1, qb[g][1], s, 0, 0, 0);
        S[jc] = s;
      }
      __builtin_amdgcn_s_setprio(0);

      // per-jc: softmax (register P) -> PV MFMAs
      #pragma unroll
      for (int jc = 0; jc < 4; jc++){
        float ev[4];
        #pragma unroll
        for (int rr = 0; rr < 4; rr++){
          float av, align;
          if (PRE){
            align = bf2f(al4[jc][rr]);
            av    = bf2f(aj4[jc][rr]);
          } else {
            float4 a4 = ad4[jc];
            av = (rr == 0) ? a4.x : (rr == 1) ? a4.y : (rr == 2) ? a4.z : a4.w;
            unsigned u = cs4[jc][rr];
            align = cAq[g] * asf(u << 16) + sAq[g] * asf(u & 0xffff0000u);
          }
          float z2 = fmaf(align, w0m, fmaf(av, w1m, wbm));    // 2*log2e*z
          float e2 = __builtin_amdgcn_exp2f(z2);              // e^{2z}
          float rc = __builtin_amdgcn_rcpf(e2 + 1.f);
          float bias2 = fmaf(-TWO_LOG2E_, rc, BIAS_C_);       // log2e*(tanh(z) - M0)
          float sv = (av > 0.f ? S[jc][rr] : -1e30f) + bias2;
          float e = __builtin_amdgcn_exp2f(sv);
          ev[rr] = e;
          lsum[g] += e;
        }
        union { unsigned u2[2]; bf16x4 v4; } pu;
        pu.u2[0] = cvt_pk_bf16(ev[0], ev[1]);
        pu.u2[1] = cvt_pk_bf16(ev[2], ev[3]);
        bf16x4 pb = pu.v4;

        // PV: OT[g][db] += V^T . P^T, depth k = jc*16 + quad*4 + j
        __builtin_amdgcn_s_setprio(1);
        #pragma unroll
        for (int db = 0; db < 4; db++){
          bf16x4 va = *(const bf16x4*)(V_t + (db * 16 + l16) * 76 + jc * 16 + quad * 4);
          MFMA16(OT[g][db], va, pb);
        }
        __builtin_amdgcn_s_setprio(0);
      }
    }
  }

  // epilogue per group: reduce lsum across the 4 quads, normalize, store O^T
  #pragma unroll
  for (int g = 0; g < 2; g++){
    float rs = lsum[g];
    rs += __shfl_xor(rs, 16);
    rs += __shfl_xor(rs, 32);
    float rl = 1.f / rs;
    short* op = outb + ((size_t)(b * N_) + qA + g * 64) * D_ + hh * DH_ + quad * 4;
    #pragma unroll
    for (int db = 0; db < 4; db++){
      unsigned o01 = cvt_pk_bf16(OT[g][db][0] * rl, OT[g][db][1] * rl);
      unsigned o23 = cvt_pk_bf16(OT[g][db][2] * rl, OT[g][db][3] * rl);
      *(uint2*)(op + db * 16) = make_uint2(o01, o23);
    }
  }
}

extern "C" void kernel_launch(void* const* d_in, const int* in_sizes, int n_in,
                              void* d_out, int out_size, void* d_ws, size_t ws_size,
                              hipStream_t stream)
{
  const float* nf   = (const float*)d_in[0];
  const float* adj  = (const float*)d_in[1];
  const float* wdir = (const float*)d_in[2];
  const float* brg  = (const float*)d_in[3];
  const float* Wq   = (const float*)d_in[4];
  const float* Wk   = (const float*)d_in[5];
  const float* Wv   = (const float*)d_in[6];
  const float* Wo   = (const float*)d_in[7];
  const float* lng  = (const float*)d_in[8];
  const float* lnb  = (const float*)d_in[9];
  const float* ww   = (const float*)d_in[10];
  const float* wbb  = (const float*)d_in[11];
  float* out = (float*)d_out;

  short* base = (short*)d_ws;
  size_t sh = 0;
  short* xln   = base + sh;  sh += (size_t)M_ * D_;        // reused as attn out
  short* WqkvT = base + sh;  sh += (size_t)DQKV_ * D_;
  short* WoT   = base + sh;  sh += (size_t)D_ * D_;
  short* QKV   = base + sh;  sh += (size_t)M_ * DQKV_;
  short* VT    = base + sh;  sh += (size_t)B_ * H_ * DH_ * N_;       // 14.7 MB
  unsigned* csb = (unsigned*)(base + sh); sh += (size_t)N_ * N_ * 2; // u32 = 2 shorts
  short* alignQ = base + sh; sh += (size_t)B_ * N_ * N_;   // optional (pre)
  short* adjQ   = base + sh; sh += (size_t)N_ * N_;        // optional (pre)
  size_t need_pre = sh * sizeof(short);
  bool pre = (ws_size >= need_pre);

  ln_kernel<<<M_, 256, 0, stream>>>(nf, lng, lnb, xln);
  transpose_kernel<<<dim3(14, 14, 4), 256, 0, stream>>>(Wq, Wk, Wv, Wo, WqkvT, WoT);
  prep_kernel<<<dim3(16, 16), 256, 0, stream>>>(adj, brg, wdir, csb, alignQ, adjQ, pre ? 1 : 0);
  gemm_bt<<<dim3(M_ / 128, DQKV_ / 128), 256, 0, stream>>>(xln, WqkvT, QKV, nullptr, nullptr, DQKV_, 1);
  vt_kernel<<<dim3(16, 112), 256, 0, stream>>>(QKV, VT);
  if (pre)
    attn_kernel<1><<<B_ * H_ * 8, 256, 0, stream>>>(QKV, VT, csb, adj, alignQ, adjQ, wdir, ww, wbb, xln);
  else
    attn_kernel<0><<<B_ * H_ * 8, 256, 0, stream>>>(QKV, VT, csb, adj, alignQ, adjQ, wdir, ww, wbb, xln);
  gemm_bt<<<dim3(M_ / 128, D_ / 128), 256, 0, stream>>>(xln, WoT, nullptr, out, nf, D_, 0);
}

// Round 11
// 367.029 us; speedup vs baseline: 1.0684x; 1.0684x over previous
//
#include <hip/hip_runtime.h>
#include <hip/hip_bf16.h>
#include <math.h>

#define B_ 8
#define N_ 1024
#define H_ 14
#define DH_ 64
#define D_ 896
#define M_ (B_*N_)        // 8192 rows
#define DQKV_ 2688        // 3*D_

// exp2-domain constants: 2*log2(e), log2(e)*(1 - M0) with M0 = 12
#define TWO_LOG2E_ 2.8853900817779268f
#define BIAS_C_   (-15.869645449778597f)
#define QSCALE_     0.18033688011112043f   // 0.125 * log2(e), folded into Q at GEMM epilogue
#define RAD_        0.017453292519943295f

typedef __attribute__((ext_vector_type(8))) short bf16x8;
typedef __attribute__((ext_vector_type(4))) short bf16x4;
typedef __attribute__((ext_vector_type(4))) float f32x4;

__device__ __forceinline__ float bf2f(short s){
  unsigned u = ((unsigned)(unsigned short)s) << 16;
  union { unsigned u; float f; } c; c.u = u; return c.f;
}
__device__ __forceinline__ short f2bf(float f){
  union { float f; unsigned u; } c; c.f = f;
  unsigned u = c.u;
  unsigned r = (u + 0x7FFFu + ((u >> 16) & 1u)) >> 16;
  return (short)(unsigned short)r;
}
__device__ __forceinline__ float asf(unsigned u){
  union { unsigned u; float f; } c; c.u = u; return c.f;
}
// pack 2 f32 -> 2 bf16 in one VALU op (RNE -- bit-identical to f2bf above)
__device__ __forceinline__ unsigned cvt_pk_bf16(float lo, float hi){
  unsigned r;
  asm("v_cvt_pk_bf16_f32 %0, %1, %2" : "=v"(r) : "v"(lo), "v"(hi));
  return r;
}

// 16x16x16 bf16 MFMA: builtin when available, else ISA-verified inline asm.
#if __has_builtin(__builtin_amdgcn_mfma_f32_16x16x16bf16_1k)
#define MFMA16(D, A, B) (D) = __builtin_amdgcn_mfma_f32_16x16x16bf16_1k((A), (B), (D), 0, 0, 0)
#else
#define MFMA16(D, A, B) asm("v_mfma_f32_16x16x16_bf16 %0, %1, %2, %0" : "+v"(D) : "v"(A), "v"(B))
#endif

// raw workgroup barrier: LDS visibility only (lgkm), does NOT drain vmcnt ->
// global register-prefetches stay in flight across it.
#define BAR_LDS() do { asm volatile("s_waitcnt lgkmcnt(0)" ::: "memory"); \
                       __builtin_amdgcn_s_barrier(); } while (0)

// ---------------- LayerNorm: one block per row, f32 in -> bf16 out ----------------
__global__ __launch_bounds__(256) void ln_kernel(const float* __restrict__ x,
                                                 const float* __restrict__ g,
                                                 const float* __restrict__ bb,
                                                 short* __restrict__ y)
{
  int row = blockIdx.x;
  const float* xr = x + (size_t)row * D_;
  float s = 0.f, s2 = 0.f;
  for (int i = threadIdx.x; i < D_; i += 256){
    float v = xr[i]; s += v; s2 = fmaf(v, v, s2);
  }
  #pragma unroll
  for (int off = 32; off > 0; off >>= 1){
    s  += __shfl_down(s,  off, 64);
    s2 += __shfl_down(s2, off, 64);
  }
  __shared__ float rs_[4], rs2_[4];
  int wv = threadIdx.x >> 6;
  if ((threadIdx.x & 63) == 0){ rs_[wv] = s; rs2_[wv] = s2; }
  __syncthreads();
  float ts  = rs_[0] + rs_[1] + rs_[2] + rs_[3];
  float ts2 = rs2_[0] + rs2_[1] + rs2_[2] + rs2_[3];
  float mu  = ts * (1.f / D_);
  float var = ts2 * (1.f / D_) - mu * mu;
  float rstd = rsqrtf(var + 1e-5f);
  short* yr = y + (size_t)row * D_;
  for (int i = threadIdx.x; i < D_; i += 256){
    yr[i] = f2bf((xr[i] - mu) * rstd * g[i] + bb[i]);
  }
}

// ---------------- Transpose weights: f32 W[k][n] -> bf16 Wt[n][k] ----------------
__global__ __launch_bounds__(256) void transpose_kernel(
    const float* __restrict__ Wq, const float* __restrict__ Wk,
    const float* __restrict__ Wv, const float* __restrict__ Wo,
    short* __restrict__ WqkvT, short* __restrict__ WoT)
{
  __shared__ short t[64][72];
  int z = blockIdx.z;
  const float* W = (z == 0) ? Wq : (z == 1) ? Wk : (z == 2) ? Wv : Wo;
  int kb = blockIdx.x * 64, nb = blockIdx.y * 64;
  int c0 = (threadIdx.x & 7) * 8;
  int r0 = threadIdx.x >> 3;            // 0..31
  #pragma unroll
  for (int rr = 0; rr < 64; rr += 32){
    const float* src = &W[(size_t)(kb + r0 + rr) * D_ + nb + c0];
    float4 a = *(const float4*)src;
    float4 b = *(const float4*)(src + 4);
    short* dstl = &t[r0 + rr][c0];
    dstl[0] = f2bf(a.x); dstl[1] = f2bf(a.y); dstl[2] = f2bf(a.z); dstl[3] = f2bf(a.w);
    dstl[4] = f2bf(b.x); dstl[5] = f2bf(b.y); dstl[6] = f2bf(b.z); dstl[7] = f2bf(b.w);
  }
  __syncthreads();
  short* dst = (z < 3) ? (WqkvT + (size_t)(z * D_) * D_) : WoT;
  #pragma unroll
  for (int rr = 0; rr < 64; rr += 32){
    int n = nb + r0 + rr;
    bf16x8 v;
    #pragma unroll
    for (int j = 0; j < 8; j++) v[j] = t[c0 + j][r0 + rr];
    *(bf16x8*)&dst[(size_t)n * D_ + kb + c0] = v;
  }
}

// ---------------- Prep: csb[k][q] (PRE=0) OR alignQ[b][q][k] (PRE=1) ----------------
// Swapped-layout attn consumes adj raw (f32) -> no adjT pass at all.
__global__ __launch_bounds__(256) void prep_kernel(
    const float* __restrict__ brg, const float* __restrict__ wdir,
    unsigned* __restrict__ csb, short* __restrict__ alignQ, int do_align)
{
  int kt = blockIdx.x, qt = blockIdx.y;
  __shared__ float brgS[64][65];
  __shared__ float cA_[8][64], sA_[8][64];
  int r  = threadIdx.x >> 2;          // 0..63
  int c0 = (threadIdx.x & 3) * 16;    // 0,16,32,48

  float bb[16];
  {
    const float* bp = brg + (size_t)(kt * 64 + r) * N_ + qt * 64 + c0;
    #pragma unroll
    for (int i = 0; i < 16; i += 4){
      float4 bv = *(const float4*)(bp + i);
      bb[i] = bv.x; bb[i+1] = bv.y; bb[i+2] = bv.z; bb[i+3] = bv.w;
    }
  }

  if (do_align){
    #pragma unroll
    for (int i = 0; i < 16; i++) brgS[r][c0 + i] = bb[i];
    for (int idx = threadIdx.x; idx < 512; idx += 256){
      int b = idx >> 6, qq = idx & 63;
      float A = wdir[(size_t)b * N_ + qt * 64 + qq] * RAD_;
      float s, c; __sincosf(A, &s, &c);
      sA_[b][qq] = s; cA_[b][qq] = c;
    }
    __syncthreads();
    // roles swap: r = q-local, c0 = k-local base
    float cB[16], sB[16];
    #pragma unroll
    for (int i = 0; i < 16; i++){
      float Br = (brgS[c0 + i][r] + 180.f) * RAD_;
      __sincosf(Br, &sB[i], &cB[i]);
    }
    #pragma unroll
    for (int b = 0; b < 8; b++){
      float ca = cA_[b][r], sa = sA_[b][r];
      unsigned w8[8];
      #pragma unroll
      for (int p = 0; p < 8; p++){
        float a0 = fmaf(ca, cB[2*p],     sa * sB[2*p]);
        float a1 = fmaf(ca, cB[2*p + 1], sa * sB[2*p + 1]);
        w8[p] = cvt_pk_bf16(a0, a1);
      }
      short* dst = alignQ + ((size_t)b * N_ + qt * 64 + r) * N_ + kt * 64 + c0;
      *(uint4*)dst       = make_uint4(w8[0], w8[1], w8[2], w8[3]);
      *(uint4*)(dst + 8) = make_uint4(w8[4], w8[5], w8[6], w8[7]);
    }
  } else {
    unsigned* cp = csb + (size_t)(kt * 64 + r) * N_ + qt * 64 + c0;
    #pragma unroll
    for (int i = 0; i < 16; i += 4){
      unsigned o[4];
      #pragma unroll
      for (int j = 0; j < 4; j++){
        float Br = (bb[i + j] + 180.f) * RAD_;
        float sBv, cBv; __sincosf(Br, &sBv, &cBv);
        o[j] = ((unsigned)(unsigned short)f2bf(cBv)) |
               (((unsigned)(unsigned short)f2bf(sBv)) << 16);
      }
      *(uint4*)(cp + i) = make_uint4(o[0], o[1], o[2], o[3]);
    }
  }
}

// ---------------- MFMA GEMM: C[M x N] = A[M x K] * Bt[N x K]^T ----------------
// rope path extras: (a) RoPE + Q-scale for Q/K head-columns; (b) V-region tiles
// (cols >= 2*D_) write the accumulator DIRECTLY to VT[(b,h,d)][tok] (transposed,
// same RNE rounding) and skip the QKV store -- replaces the old vt_kernel pass.
__global__ __launch_bounds__(256) void gemm_bt(const short* __restrict__ A,
                                               const short* __restrict__ Bt,
                                               short* __restrict__ C,
                                               float* __restrict__ Cf,
                                               const float* __restrict__ residf,
                                               short* __restrict__ VTo,
                                               int N, int rope)
{
  const int K = D_;
  __shared__ short As[128 * 32];
  __shared__ short Bs[128 * 32];
  int tid  = threadIdx.x;
  int wave = tid >> 6;
  int lane = tid & 63;
  int quad = lane >> 4;
  int l16  = lane & 15;
  int wr = wave >> 1, wc = wave & 1;
  int m0 = blockIdx.x * 128;
  int n0 = blockIdx.y * 128;

  f32x4 acc[4][4];
  #pragma unroll
  for (int i = 0; i < 4; i++)
    #pragma unroll
    for (int j = 0; j < 4; j++)
      acc[i][j] = (f32x4){0.f, 0.f, 0.f, 0.f};

  for (int k0 = 0; k0 < K; k0 += 32){
    __syncthreads();
    #pragma unroll
    for (int it = 0; it < 2; ++it){
      int c   = tid + it * 256;
      int row = c >> 2;
      int cc  = c & 3;
      const short* ga = A  + (size_t)(m0 + row) * K + k0 + cc * 8;
      const short* gb = Bt + (size_t)(n0 + row) * K + k0 + cc * 8;
      short* la = As + (size_t)(wave * 64 + it * 256) * 8;
      short* lb = Bs + (size_t)(wave * 64 + it * 256) * 8;
      __builtin_amdgcn_global_load_lds((const __attribute__((address_space(1))) void*)ga,
                                       (__attribute__((address_space(3))) void*)la, 16, 0, 0);
      __builtin_amdgcn_global_load_lds((const __attribute__((address_space(1))) void*)gb,
                                       (__attribute__((address_space(3))) void*)lb, 16, 0, 0);
    }
    __syncthreads();

    bf16x8 af[4], bfr[4];
    #pragma unroll
    for (int i = 0; i < 4; i++)
      af[i] = *(const bf16x8*)(As + (size_t)(wr * 64 + i * 16 + l16) * 32 + quad * 8);
    #pragma unroll
    for (int j = 0; j < 4; j++)
      bfr[j] = *(const bf16x8*)(Bs + (size_t)(wc * 64 + j * 16 + l16) * 32 + quad * 8);
    #pragma unroll
    for (int i = 0; i < 4; i++)
      #pragma unroll
      for (int j = 0; j < 4; j++)
        acc[i][j] = __builtin_amdgcn_mfma_f32_16x16x32_bf16(af[i], bfr[j], acc[i][j], 0, 0, 0);
  }

  int cb  = n0 + wc * 64;              // head base col (64-aligned)
  if (rope){
    int mat = cb / D_;                 // 0=Q, 1=K, 2=V
    if (mat < 2){
      float scale = (mat == 0) ? QSCALE_ : 1.0f;
      float invf0 = exp2f(-0.4152410118609203f * (float)l16);  // 10000^(-l16/32)
      float invf1 = invf0 * 0.01f;                             // 10000^(-(16+l16)/32)
      #pragma unroll
      for (int i = 0; i < 4; i++){
        #pragma unroll
        for (int rr = 0; rr < 4; rr++){
          int r = m0 + wr * 64 + i * 16 + quad * 4 + rr;
          float nseq = (float)(r & (N_ - 1));
          float s0, c0v, s1, c1v;
          __sincosf(nseq * invf0, &s0, &c0v);
          __sincosf(nseq * invf1, &s1, &c1v);
          float x1 = acc[i][0][rr], x2 = acc[i][2][rr];
          acc[i][0][rr] = (x1 * c0v - x2 * s0) * scale;
          acc[i][2][rr] = (x2 * c0v + x1 * s0) * scale;
          x1 = acc[i][1][rr]; x2 = acc[i][3][rr];
          acc[i][1][rr] = (x1 * c1v - x2 * s1) * scale;
          acc[i][3][rr] = (x2 * c1v + x1 * s1) * scale;
        }
      }
    }
  }

  if (rope && cb >= 2 * D_){
    // V tile -> VT[(b*H + h)*DH + d][tok], 4 tokens per 8B store (RNE like f2bf)
    int h   = (cb - 2 * D_) >> 6;
    int bb2 = m0 >> 10;                          // batch (128-row tile within one batch)
    int nb_ = (m0 & (N_ - 1)) + wr * 64 + quad * 4;
    #pragma unroll
    for (int i = 0; i < 4; i++){
      #pragma unroll
      for (int j = 0; j < 4; j++){
        int d = j * 16 + l16;
        short* vp = VTo + ((size_t)(bb2 * H_ + h) * DH_ + d) * N_ + nb_ + i * 16;
        unsigned o01 = cvt_pk_bf16(acc[i][j][0], acc[i][j][1]);
        unsigned o23 = cvt_pk_bf16(acc[i][j][2], acc[i][j][3]);
        *(uint2*)vp = make_uint2(o01, o23);
      }
    }
  } else {
    #pragma unroll
    for (int i = 0; i < 4; i++){
      #pragma unroll
      for (int rr = 0; rr < 4; rr++){
        int r = m0 + wr * 64 + i * 16 + quad * 4 + rr;
        size_t rowoff = (size_t)r * N;
        #pragma unroll
        for (int j = 0; j < 4; j++){
          int cidx = cb + j * 16 + l16;
          float v = acc[i][j][rr];
          if (Cf){
            Cf[rowoff + cidx] = v + residf[rowoff + cidx];
          } else {
            C[rowoff + cidx] = f2bf(v);
          }
        }
      }
    }
  }
}

// ---------------- Swapped-operand flash attention with LDS staging (r7 verbatim) ----
// Proven 141.9us config: S^T = mfma32(K from LDS, Q regs) -> register-P via cvt_pk
// -> PV mfma16(V_t frag, P) ; 2 raw lgkm-barriers/iter; K/V + bias prefetched 1
// tile ahead; all fragments from LDS; vmcnt never drained at barriers.
template<int PRE>
__global__ __launch_bounds__(256, 2) void attn_kernel(
    const short* __restrict__ QKV,
    const short* __restrict__ VT,       // [(b*H+h)*64 + d][tok] bf16
    const unsigned* __restrict__ csb,   // [k][q] packed (cosB, sinB)   (PRE=0)
    const float* __restrict__ adjF,     // [q][k] f32 (raw input)
    const short* __restrict__ alignQ,   // [b][q][k] bf16               (PRE=1)
    const float* __restrict__ wind_dirs,
    const float* __restrict__ wind_w,
    const float* __restrict__ wind_b,
    short* __restrict__ outb)
{
  __shared__ short K_s[64 * 72];       // K[k][d]
  __shared__ short V_t[64 * 76];       // V^T[d][k]

  int bid = blockIdx.x;
  // bid = qt*112 + hh*8 + b  (112%8==0 -> XCD = bid%8 = b)
  int qt  = bid / 112;
  int rem = bid - qt * 112;
  int hh  = rem >> 3;
  int b   = rem & 7;
  int q0  = qt * 64;
  int kt0 = qt;                        // staggered start tile (order-invariant)

  int t    = threadIdx.x;
  int w    = t >> 6;          // 0..3
  int lane = t & 63;
  int quad = lane >> 4;
  int l16  = lane & 15;
  int q    = q0 + w * 16 + l16;        // this lane's q row

  // Q B-frags for x32 QK: B[n=q=l16][d = quad*8+j], halves d<32 / d>=32
  const short* qp = QKV + ((size_t)(b * N_) + q) * DQKV_ + hh * DH_ + quad * 8;
  bf16x8 qb0 = *(const bf16x8*)qp;
  bf16x8 qb1 = *(const bf16x8*)(qp + 32);

  float cAq = 0.f, sAq = 0.f;
  if (!PRE){
    float A = wind_dirs[(size_t)b * N_ + q] * RAD_;
    sAq = __sinf(A); cAq = __cosf(A);
  }
  float w0m = wind_w[hh]      * TWO_LOG2E_;
  float w1m = wind_w[H_ + hh] * TWO_LOG2E_;
  float wbm = wind_b[hh]      * TWO_LOG2E_;

  float lsum = 0.f;
  f32x4 OT[4];                         // OT[db]: O[d=db*16+quad*4+rr][q=l16]
  #pragma unroll
  for (int db = 0; db < 4; db++) OT[db] = (f32x4){0.f, 0.f, 0.f, 0.f};

  // staging: 4 threads/row, 2x16B each
  int sr = t >> 2, sc = (t & 3) * 16;
  const short* kg0 = QKV + ((size_t)(b * N_) + sr) * DQKV_ + D_ + hh * DH_ + sc;
  const short* vg0 = VT + ((size_t)(b * H_ + hh) * DH_ + sr) * N_ + sc;

  // per-lane bias row pointers ([q][k] layouts, k-contiguous)
  const short* al2 = alignQ + ((size_t)b * N_ + q) * N_ + quad * 4;
  const float* ad2 = adjF + (size_t)q * N_ + quad * 4;

  int k0f = kt0 * 64;
  // prologue prefetch (tile kt0): K/V staging registers
  bf16x8 pkA = *(const bf16x8*)(kg0 + (size_t)k0f * DQKV_);
  bf16x8 pkB = *(const bf16x8*)(kg0 + (size_t)k0f * DQKV_ + 8);
  bf16x8 pvA = *(const bf16x8*)(vg0 + k0f);
  bf16x8 pvB = *(const bf16x8*)(vg0 + k0f + 8);

  // prologue prefetch (tile kt0): bias inputs
  float4 ad4[4]; bf16x4 al4[4]; unsigned cs4[4][4];
  #pragma unroll
  for (int jc = 0; jc < 4; jc++){
    ad4[jc] = *(const float4*)(ad2 + k0f + jc * 16);
    if (PRE){
      al4[jc] = *(const bf16x4*)(al2 + k0f + jc * 16);
    } else {
      #pragma unroll
      for (int rr = 0; rr < 4; rr++)
        cs4[jc][rr] = csb[(size_t)(k0f + jc * 16 + quad * 4 + rr) * N_ + q];
    }
  }

  for (int it = 0; it < 16; ++it){
    int kn = (((it + 1 + kt0) & 15)) * 64;   // next tile base (wraps on last iter)

    BAR_LDS();                         // WAR: prev tile's LDS reads all consumed
    *(bf16x8*)(K_s + sr * 72 + sc)     = pkA;
    *(bf16x8*)(K_s + sr * 72 + sc + 8) = pkB;
    *(bf16x8*)(V_t + sr * 76 + sc)     = pvA;
    *(bf16x8*)(V_t + sr * 76 + sc + 8) = pvB;
    BAR_LDS();                         // RAW: staging visible; vmcnt NOT drained

    // issue next tile's K/V prefetch -- in flight under the whole compute phase
    pkA = *(const bf16x8*)(kg0 + (size_t)kn * DQKV_);
    pkB = *(const bf16x8*)(kg0 + (size_t)kn * DQKV_ + 8);
    pvA = *(const bf16x8*)(vg0 + kn);
    pvB = *(const bf16x8*)(vg0 + kn + 8);

    // S^T = K . Q^T  (lane: k = jc*16 + quad*4 + rr, q = l16)
    f32x4 S[4];
    __builtin_amdgcn_s_setprio(1);
    #pragma unroll
    for (int jc = 0; jc < 4; jc++){
      bf16x8 ka0 = *(const bf16x8*)(K_s + (jc * 16 + l16) * 72 + quad * 8);
      bf16x8 ka1 = *(const bf16x8*)(K_s + (jc * 16 + l16) * 72 + 32 + quad * 8);
      f32x4 s = (f32x4){0.f, 0.f, 0.f, 0.f};
      s = __builtin_amdgcn_mfma_f32_16x16x32_bf16(ka0, qb0, s, 0, 0, 0);
      s = __builtin_amdgcn_mfma_f32_16x16x32_bf16(ka1, qb1, s, 0, 0, 0);
      S[jc] = s;
    }
    __builtin_amdgcn_s_setprio(0);

    // per-jc: softmax (register P) -> PV MFMAs; bias prefetch after consumption
    #pragma unroll
    for (int jc = 0; jc < 4; jc++){
      float a4[4] = { ad4[jc].x, ad4[jc].y, ad4[jc].z, ad4[jc].w };
      float ev[4];
      #pragma unroll
      for (int rr = 0; rr < 4; rr++){
        float av = a4[rr];
        float align;
        if (PRE){
          align = bf2f(al4[jc][rr]);
        } else {
          unsigned u = cs4[jc][rr];
          align = cAq * asf(u << 16) + sAq * asf(u & 0xffff0000u);
        }
        float z2 = fmaf(align, w0m, fmaf(av, w1m, wbm));    // 2*log2e*z
        float e2 = __builtin_amdgcn_exp2f(z2);              // e^{2z}
        float rc = __builtin_amdgcn_rcpf(e2 + 1.f);
        float bias2 = fmaf(-TWO_LOG2E_, rc, BIAS_C_);       // log2e*(tanh(z) - M0)
        float sv = (av > 0.f ? S[jc][rr] : -1e30f) + bias2;
        float e = __builtin_amdgcn_exp2f(sv);
        ev[rr] = e;
        lsum += e;
      }
      union { unsigned u2[2]; bf16x4 v4; } pu;
      pu.u2[0] = cvt_pk_bf16(ev[0], ev[1]);
      pu.u2[1] = cvt_pk_bf16(ev[2], ev[3]);
      bf16x4 pb = pu.v4;

      // prefetch next tile's bias inputs for this jc (consumed next iteration)
      ad4[jc] = *(const float4*)(ad2 + kn + jc * 16);
      if (PRE){
        al4[jc] = *(const bf16x4*)(al2 + kn + jc * 16);
      } else {
        #pragma unroll
        for (int rr = 0; rr < 4; rr++)
          cs4[jc][rr] = csb[(size_t)(kn + jc * 16 + quad * 4 + rr) * N_ + q];
      }

      // PV: OT[db] += V^T . P^T, k-depth = jc*16 + quad*4 + j (P direct from regs)
      __builtin_amdgcn_s_setprio(1);
      #pragma unroll
      for (int db = 0; db < 4; db++){
        bf16x4 va = *(const bf16x4*)(V_t + (db * 16 + l16) * 76 + jc * 16 + quad * 4);
        MFMA16(OT[db], va, pb);
      }
      __builtin_amdgcn_s_setprio(0);
    }
  }

  // reduce lsum across the 4 quads (same q = l16), normalize, store O^T
  lsum += __shfl_xor(lsum, 16);
  lsum += __shfl_xor(lsum, 32);
  float rl = 1.f / lsum;

  short* op = outb + ((size_t)(b * N_) + q) * D_ + hh * DH_ + quad * 4;
  #pragma unroll
  for (int db = 0; db < 4; db++){
    unsigned o01 = cvt_pk_bf16(OT[db][0] * rl, OT[db][1] * rl);
    unsigned o23 = cvt_pk_bf16(OT[db][2] * rl, OT[db][3] * rl);
    *(uint2*)(op + db * 16) = make_uint2(o01, o23);
  }
}

extern "C" void kernel_launch(void* const* d_in, const int* in_sizes, int n_in,
                              void* d_out, int out_size, void* d_ws, size_t ws_size,
                              hipStream_t stream)
{
  const float* nf   = (const float*)d_in[0];
  const float* adj  = (const float*)d_in[1];
  const float* wdir = (const float*)d_in[2];
  const float* brg  = (const float*)d_in[3];
  const float* Wq   = (const float*)d_in[4];
  const float* Wk   = (const float*)d_in[5];
  const float* Wv   = (const float*)d_in[6];
  const float* Wo   = (const float*)d_in[7];
  const float* lng  = (const float*)d_in[8];
  const float* lnb  = (const float*)d_in[9];
  const float* ww   = (const float*)d_in[10];
  const float* wbb  = (const float*)d_in[11];
  float* out = (float*)d_out;

  short* base = (short*)d_ws;
  size_t sh = 0;
  short* xln   = base + sh;  sh += (size_t)M_ * D_;        // reused as attn out
  short* WqkvT = base + sh;  sh += (size_t)DQKV_ * D_;
  short* WoT   = base + sh;  sh += (size_t)D_ * D_;
  short* QKV   = base + sh;  sh += (size_t)M_ * DQKV_;
  short* VT    = base + sh;  sh += (size_t)B_ * H_ * DH_ * N_;       // 14.7 MB
  unsigned* csb = (unsigned*)(base + sh); sh += (size_t)N_ * N_ * 2; // u32 = 2 shorts
  short* alignQ = base + sh; sh += (size_t)B_ * N_ * N_;   // optional (pre)
  size_t need_pre = sh * sizeof(short);
  bool pre = (ws_size >= need_pre);

  ln_kernel<<<M_, 256, 0, stream>>>(nf, lng, lnb, xln);
  transpose_kernel<<<dim3(14, 14, 4), 256, 0, stream>>>(Wq, Wk, Wv, Wo, WqkvT, WoT);
  prep_kernel<<<dim3(16, 16), 256, 0, stream>>>(brg, wdir, csb, alignQ, pre ? 1 : 0);
  gemm_bt<<<dim3(M_ / 128, DQKV_ / 128), 256, 0, stream>>>(xln, WqkvT, QKV, nullptr, nullptr, VT, DQKV_, 1);
  if (pre)
    attn_kernel<1><<<B_ * H_ * 16, 256, 0, stream>>>(QKV, VT, csb, adj, alignQ, wdir, ww, wbb, xln);
  else
    attn_kernel<0><<<B_ * H_ * 16, 256, 0, stream>>>(QKV, VT, csb, adj, alignQ, wdir, ww, wbb, xln);
  gemm_bt<<<dim3(M_ / 128, D_ / 128), 256, 0, stream>>>(xln, WoT, nullptr, out, nf, nullptr, D_, 0);
}